// Round 6
// baseline (324.328 us; speedup 1.0000x reference)
//
#include <hip/hip_runtime.h>

#define IN_DIM   128
#define NH       8
#define HD       16
#define OUTD     128   // NH*HD
#define QKVD     384   // Q|K|V per node, bf16

typedef unsigned short ushort_t;
typedef unsigned int   uint_t;
typedef __bf16 bf16x8 __attribute__((ext_vector_type(8)));
typedef float  f32x4  __attribute__((ext_vector_type(4)));

__device__ __forceinline__ float bf2f(ushort_t u) {
    return __uint_as_float(((uint_t)u) << 16);
}
__device__ __forceinline__ ushort_t f2bf(float f) {
    uint_t u = __float_as_uint(f);
    u += 0x7FFFu + ((u >> 16) & 1u);      // RNE
    return (ushort_t)(u >> 16);
}

// ---------------------------------------------------------------------------
// prep_w: W[k][c] fp32 (3 mats) -> Wt[col][k] bf16, col in [0,384).
// Also zeroes P[N] and desc[128] (replaces a hipMemsetAsync dispatch).
// ---------------------------------------------------------------------------
__global__ __launch_bounds__(256) void prep_w(
    const float* __restrict__ Wq, const float* __restrict__ Wk,
    const float* __restrict__ Wv, ushort_t* __restrict__ Wt,
    int* __restrict__ P, unsigned long long* __restrict__ desc, int N)
{
    __shared__ float ld[32][33];
    int mat  = blockIdx.x >> 4;
    int tile = blockIdx.x & 15;
    int k0 = (tile >> 2) * 32, c0 = (tile & 3) * 32;
    const float* W = (mat == 0) ? Wq : (mat == 1) ? Wk : Wv;
    int t = threadIdx.x;
    {
        int k = t >> 3, c4 = (t & 7) * 4;
        float4 f = *(const float4*)&W[(size_t)(k0 + k) * 128 + c0 + c4];
        ld[k][c4 + 0] = f.x; ld[k][c4 + 1] = f.y;
        ld[k][c4 + 2] = f.z; ld[k][c4 + 3] = f.w;
    }
    __syncthreads();
    {
        int c = t >> 3, kg = (t & 7) * 4;
        union { ushort_t h[4]; uint2 u; } o;
        o.h[0] = f2bf(ld[kg + 0][c]); o.h[1] = f2bf(ld[kg + 1][c]);
        o.h[2] = f2bf(ld[kg + 2][c]); o.h[3] = f2bf(ld[kg + 3][c]);
        *(uint2*)&Wt[((size_t)(mat * 128 + c0 + c)) * 128 + k0 + kg] = o.u;
    }
    // fused zeroing (independent of the transpose work)
    int t0 = blockIdx.x * 256 + threadIdx.x;
    for (int i = t0; i < N; i += 48 * 256) P[i] = 0;
    if (t0 < 128) desc[t0] = 0ULL;
}

// ---------------------------------------------------------------------------
// gemm_histo: blocks [0, nhisto) run the degree histogram FIRST (so the
// atomic stream overlaps the gemm blocks instead of trailing them).
// Blocks >= nhisto do the QKV MFMA GEMM: 64 rows x 384 cols, 6 waves.
// A staged in LDS k-packed [kc16][row 65-pad][8]; B direct from global Wt.
// Epilogue: LDS transpose in 4 quarters of 16 rows (LDS stays 16.6 KB ->
// 5 blocks/CU) -> coalesced dwordx4 stores into qkv[N][384] bf16.
// ---------------------------------------------------------------------------
__global__ __launch_bounds__(384) void gemm_histo(
    const float* __restrict__ x, const ushort_t* __restrict__ Wt,
    const float* __restrict__ bq, const float* __restrict__ bk,
    const float* __restrict__ bv,
    const int* __restrict__ ei, int* __restrict__ P,
    ushort_t* __restrict__ qkv,
    int N, int E, int nhisto)
{
    if ((int)blockIdx.x < nhisto) {
        int e0 = ((int)blockIdx.x * 384 + threadIdx.x) * 4;
        if (e0 + 4 <= E) {
            int4 d = *(const int4*)&ei[E + e0];
            atomicAdd(&P[d.x], 1); atomicAdd(&P[d.y], 1);
            atomicAdd(&P[d.z], 1); atomicAdd(&P[d.w], 1);
        } else {
            for (int e = e0; e < E; e++) atomicAdd(&P[ei[E + e]], 1);
        }
        return;
    }

    __shared__ ushort_t sh[8320];     // 16640 B: staging 8312, epilogue 6272

    const int tid  = threadIdx.x;
    const int row0 = ((int)blockIdx.x - nhisto) * 64;

    // ---- stage A: 64 rows x 128 k, bf16, k-packed [kc(16)][row(65 pad)][8] ----
    for (int ch = tid; ch < 1024; ch += 384) {
        int row = ch >> 4;
        int kc  = ch & 15;
        int grow = row0 + row; if (grow > N - 1) grow = N - 1;
        const float* xp = x + (size_t)grow * IN_DIM + kc * 8;
        float4 f0 = *(const float4*)xp;
        float4 f1 = *(const float4*)(xp + 4);
        union { ushort_t h[8]; uint4 u; } tt;
        tt.h[0] = f2bf(f0.x); tt.h[1] = f2bf(f0.y);
        tt.h[2] = f2bf(f0.z); tt.h[3] = f2bf(f0.w);
        tt.h[4] = f2bf(f1.x); tt.h[5] = f2bf(f1.y);
        tt.h[6] = f2bf(f1.z); tt.h[7] = f2bf(f1.w);
        *(uint4*)&sh[(kc * 65 + row) * 8] = tt.u;
    }
    __syncthreads();

    const int w    = tid >> 6;        // wave 0..5
    const int quad = (tid >> 4) & 3;
    const int l15  = tid & 15;
    const int colg = w << 6;          // global col base 0..320

    f32x4 acc[4][4];
#pragma unroll
    for (int r = 0; r < 4; r++)
#pragma unroll
        for (int cs = 0; cs < 4; cs++) acc[r][cs] = (f32x4){0.f, 0.f, 0.f, 0.f};

    for (int kt = 0; kt < 4; kt++) {
        bf16x8 bfr[4], af[4];
#pragma unroll
        for (int cs = 0; cs < 4; cs++) {
            int col = colg + cs * 16 + l15;
            bfr[cs] = *(const bf16x8*)&Wt[(size_t)col * 128 + kt * 32 + quad * 8];
        }
        int kc = kt * 4 + quad;
#pragma unroll
        for (int r = 0; r < 4; r++)
            af[r] = *(const bf16x8*)&sh[(kc * 65 + r * 16 + l15) * 8];
#pragma unroll
        for (int r = 0; r < 4; r++)
#pragma unroll
            for (int cs = 0; cs < 4; cs++)
                acc[r][cs] = __builtin_amdgcn_mfma_f32_16x16x32_bf16(
                    af[r], bfr[cs], acc[r][cs], 0, 0, 0);
    }

    // ---- epilogue: bias + cvt, LDS transpose in 4 quarters of 16 rows ----
    const int mat = w >> 1;           // 0=Q,1=K,2=V
    const float* Bp = (mat == 0) ? bq : (mat == 1) ? bk : bv;
    float bias[4];
#pragma unroll
    for (int cs = 0; cs < 4; cs++)
        bias[cs] = Bp[((w & 1) << 6) + cs * 16 + l15];

#define EPS 392   // padded row stride (bf16 units)
#pragma unroll
    for (int qq = 0; qq < 4; qq++) {
        __syncthreads();   // LDS free (staging reads / previous quarter done)
        int lrow = quad << 2;          // acc[qq] covers tile rows 16qq..16qq+16
#pragma unroll
        for (int cs = 0; cs < 4; cs++) {
            int col = (w << 6) + cs * 16 + l15;
#pragma unroll
            for (int reg = 0; reg < 4; reg++)
                sh[(lrow + reg) * EPS + col] = f2bf(acc[qq][cs][reg] + bias[cs]);
        }
        __syncthreads();
        // read out: 16 rows x 384 cols = 768 chunks of 8 bf16; 2 per thread
#pragma unroll
        for (int i = 0; i < 2; i++) {
            int c = tid + i * 384;
            int row = c / 48;
            int col = (c % 48) * 8;
            int grow = row0 + qq * 16 + row;
            if (grow < N) {
                uint4 val = *(const uint4*)&sh[row * EPS + col];
                *(uint4*)&qkv[(size_t)grow * QKVD + col] = val;
            }
        }
    }
#undef EPS
}

// ---------------------------------------------------------------------------
// Single-pass exclusive scan over P[N] (decoupled lookback).
// ---------------------------------------------------------------------------
__global__ __launch_bounds__(1024) void scan_onepass(
    int* __restrict__ P, unsigned long long* __restrict__ desc, int N)
{
    __shared__ int sdata[1024];
    __shared__ int s_prefix;
    int b = blockIdx.x;
    int i = b * 1024 + threadIdx.x;
    int v = (i < N) ? P[i] : 0;
    sdata[threadIdx.x] = v;
    __syncthreads();
    for (int off = 1; off < 1024; off <<= 1) {
        int t = (threadIdx.x >= off) ? sdata[threadIdx.x - off] : 0;
        __syncthreads();
        sdata[threadIdx.x] += t;
        __syncthreads();
    }
    int incl  = sdata[threadIdx.x];
    int total = sdata[1023];

    if (threadIdx.x == 0) {
        unsigned long long st1 = ((unsigned long long)((b == 0) ? 2 : 1) << 32)
                                 | (uint_t)total;
        __hip_atomic_store(&desc[b], st1, __ATOMIC_RELEASE, __HIP_MEMORY_SCOPE_AGENT);
        int prefix = 0;
        if (b > 0) {
            int bb = b - 1;
            for (;;) {
                unsigned long long d = __hip_atomic_load(
                    &desc[bb], __ATOMIC_ACQUIRE, __HIP_MEMORY_SCOPE_AGENT);
                uint_t st = (uint_t)(d >> 32);
                if (st == 0) continue;
                prefix += (int)(uint_t)(d & 0xFFFFFFFFu);
                if (st == 2) break;
                bb--;
            }
            __hip_atomic_store(&desc[b],
                ((unsigned long long)2 << 32) | (uint_t)(prefix + total),
                __ATOMIC_RELEASE, __HIP_MEMORY_SCOPE_AGENT);
        }
        s_prefix = prefix;
    }
    __syncthreads();
    if (i < N) P[i] = s_prefix + incl - v;   // exclusive
}

__global__ __launch_bounds__(256) void scatter(
    const int* __restrict__ ei, int* __restrict__ P,
    int* __restrict__ sorted_src, int E)
{
    int e0 = (blockIdx.x * 256 + threadIdx.x) * 4;
    if (e0 + 4 <= E) {
        int4 s4 = *(const int4*)&ei[e0];
        int4 d4 = *(const int4*)&ei[E + e0];
        sorted_src[atomicAdd(&P[d4.x], 1)] = s4.x;
        sorted_src[atomicAdd(&P[d4.y], 1)] = s4.y;
        sorted_src[atomicAdd(&P[d4.z], 1)] = s4.z;
        sorted_src[atomicAdd(&P[d4.w], 1)] = s4.w;
    } else {
        for (int e = e0; e < E; e++) {
            int pos = atomicAdd(&P[ei[E + e]], 1);
            sorted_src[pos] = ei[e];
        }
    }
}

// ---------------------------------------------------------------------------
// Segmented attention reduce + fused normalize. SIXTEEN lanes per node
// (4 nodes/wave): lane g holds dims [8g, 8g+8). Head h = dims 16h..16h+16
// lives on lane pair {2h, 2h+1} -> one shfl_xor(1) completes the dot.
// P[n] == rowptr[n+1] after scatter; segment n = [P[n-1], P[n]), P[-1]=0.
// ---------------------------------------------------------------------------
__global__ __launch_bounds__(256) void segment_attn(
    const ushort_t* __restrict__ qkv,
    const int* __restrict__ P, const int* __restrict__ sorted_src,
    float* __restrict__ out, int N)
{
    int n = (blockIdx.x * 256 + threadIdx.x) >> 4;    // node = 16-lane group
    int g = threadIdx.x & 15;
    if (n >= N) return;
    int start = (n == 0) ? 0 : P[n - 1];
    int end   = P[n];
    int deg   = end - start;

    // Q: lane g holds dims 8g..8g+8
    const uint_t* qrow = (const uint_t*)(qkv + (size_t)n * QKVD);
    uint4 qu = *(const uint4*)(qrow + g * 4);
    float q0 = bf2f((ushort_t)(qu.x & 0xFFFF)), q1 = bf2f((ushort_t)(qu.x >> 16));
    float q2 = bf2f((ushort_t)(qu.y & 0xFFFF)), q3 = bf2f((ushort_t)(qu.y >> 16));
    float q4 = bf2f((ushort_t)(qu.z & 0xFFFF)), q5 = bf2f((ushort_t)(qu.z >> 16));
    float q6 = bf2f((ushort_t)(qu.w & 0xFFFF)), q7 = bf2f((ushort_t)(qu.w >> 16));

    float a0 = 0.f, a1 = 0.f, a2 = 0.f, a3 = 0.f;
    float a4 = 0.f, a5 = 0.f, a6 = 0.f, a7 = 0.f, z = 0.f;

    int myidx = (g < deg) ? sorted_src[start + g] : 0;
    int wbase = (threadIdx.x & 63) & 48;     // group base lane within wave

#define PROC(ku, vu)                                                       \
    {                                                                      \
        float p = bf2f((ushort_t)((ku).x & 0xFFFF)) * q0                   \
                + bf2f((ushort_t)((ku).x >> 16))    * q1                   \
                + bf2f((ushort_t)((ku).y & 0xFFFF)) * q2                   \
                + bf2f((ushort_t)((ku).y >> 16))    * q3                   \
                + bf2f((ushort_t)((ku).z & 0xFFFF)) * q4                   \
                + bf2f((ushort_t)((ku).z >> 16))    * q5                   \
                + bf2f((ushort_t)((ku).w & 0xFFFF)) * q6                   \
                + bf2f((ushort_t)((ku).w >> 16))    * q7;                  \
        p += __shfl_xor(p, 1);                                             \
        p = fminf(fmaxf(p * 0.25f, -5.f), 5.f);                            \
        float s = __expf(p);                                               \
        a0 += bf2f((ushort_t)((vu).x & 0xFFFF)) * s;                       \
        a1 += bf2f((ushort_t)((vu).x >> 16))    * s;                       \
        a2 += bf2f((ushort_t)((vu).y & 0xFFFF)) * s;                       \
        a3 += bf2f((ushort_t)((vu).y >> 16))    * s;                       \
        a4 += bf2f((ushort_t)((vu).z & 0xFFFF)) * s;                       \
        a5 += bf2f((ushort_t)((vu).z >> 16))    * s;                       \
        a6 += bf2f((ushort_t)((vu).w & 0xFFFF)) * s;                       \
        a7 += bf2f((ushort_t)((vu).w >> 16))    * s;                       \
        z += s;                                                            \
    }

    int cnt = (deg < 16) ? deg : 16;
    int t = 0;
    for (; t + 2 <= cnt; t += 2) {
        int s0 = __shfl(myidx, wbase + t);
        int s1 = __shfl(myidx, wbase + t + 1);
        const uint_t* kv0 = (const uint_t*)(qkv + (size_t)s0 * QKVD + 128);
        const uint_t* kv1 = (const uint_t*)(qkv + (size_t)s1 * QKVD + 128);
        uint4 ku0 = *(const uint4*)(kv0 + g * 4);
        uint4 ku1 = *(const uint4*)(kv1 + g * 4);
        uint4 vu0 = *(const uint4*)(kv0 + 64 + g * 4);
        uint4 vu1 = *(const uint4*)(kv1 + 64 + g * 4);
        PROC(ku0, vu0); PROC(ku1, vu1);
    }
    if (t < cnt) {
        int s0 = __shfl(myidx, wbase + t);
        const uint_t* kv0 = (const uint_t*)(qkv + (size_t)s0 * QKVD + 128);
        uint4 ku0 = *(const uint4*)(kv0 + g * 4);
        uint4 vu0 = *(const uint4*)(kv0 + 64 + g * 4);
        PROC(ku0, vu0);
    }
    for (int j = start + 16; j < end; j++) {   // deg>16 fallback
        int s0 = sorted_src[j];
        const uint_t* kv0 = (const uint_t*)(qkv + (size_t)s0 * QKVD + 128);
        uint4 ku0 = *(const uint4*)(kv0 + g * 4);
        uint4 vu0 = *(const uint4*)(kv0 + 64 + g * 4);
        PROC(ku0, vu0);
    }
#undef PROC

    float inv = 1.f / (z + 1e-6f);
    float4 o0 = {a0 * inv, a1 * inv, a2 * inv, a3 * inv};
    float4 o1 = {a4 * inv, a5 * inv, a6 * inv, a7 * inv};
    float* ob = out + (size_t)n * OUTD + g * 8;
    *(float4*)ob = o0;
    *(float4*)(ob + 4) = o1;
}

extern "C" void kernel_launch(void* const* d_in, const int* in_sizes, int n_in,
                              void* d_out, int out_size, void* d_ws, size_t ws_size,
                              hipStream_t stream) {
    const float* x  = (const float*)d_in[0];
    const int*   ei = (const int*)d_in[1];
    const float* Wq = (const float*)d_in[4];
    const float* bq = (const float*)d_in[5];
    const float* Wk = (const float*)d_in[6];
    const float* bk = (const float*)d_in[7];
    const float* Wv = (const float*)d_in[8];
    const float* bv = (const float*)d_in[9];
    float* out = (float*)d_out;

    const int N = in_sizes[0] / IN_DIM;     // 100000
    const int E = in_sizes[1] / 2;          // 800000

    char* wsb = (char*)d_ws;
    ushort_t* qkv = (ushort_t*)wsb;                          // N*384 bf16
    ushort_t* Wt  = qkv + (size_t)N * QKVD;                  // 384*128 bf16
    int* P = (int*)(Wt + 384 * 128);                         // N ints
    unsigned long long* desc = (unsigned long long*)((char*)P + (size_t)N * 4);
    int* sorted = (int*)((char*)desc + 1024);                // E ints

    const int ngemm  = (N + 63) / 64;                 // 1563
    const int nhisto = (E + 384 * 4 - 1) / (384 * 4); // 521 -> covers E in 1 pass
    const int NB     = (N + 1023) / 1024;             // 98 scan blocks

    prep_w<<<48, 256, 0, stream>>>(Wq, Wk, Wv, Wt, P, desc, N);
    gemm_histo<<<nhisto + ngemm, 384, 0, stream>>>(
        x, Wt, bq, bk, bv, ei, P, qkv, N, E, nhisto);
    scan_onepass<<<NB, 1024, 0, stream>>>(P, desc, N);
    scatter<<<(E / 4 + 255) / 256, 256, 0, stream>>>(ei, P, sorted, E);
    segment_attn<<<((size_t)N * 16 + 255) / 256, 256, 0, stream>>>(
        qkv, P, sorted, out, N);
}

// Round 7
// 304.724 us; speedup vs baseline: 1.0643x; 1.0643x over previous
//
#include <hip/hip_runtime.h>

#define IN_DIM   128
#define NH       8
#define HD       16
#define OUTD     128   // NH*HD
#define QKVD     384   // Q|K|V per node, bf16

typedef unsigned short ushort_t;
typedef unsigned int   uint_t;
typedef __bf16 bf16x8 __attribute__((ext_vector_type(8)));
typedef float  f32x4  __attribute__((ext_vector_type(4)));

__device__ __forceinline__ float bf2f(ushort_t u) {
    return __uint_as_float(((uint_t)u) << 16);
}
__device__ __forceinline__ ushort_t f2bf(float f) {
    uint_t u = __float_as_uint(f);
    u += 0x7FFFu + ((u >> 16) & 1u);      // RNE
    return (ushort_t)(u >> 16);
}

// ---------------------------------------------------------------------------
// prep_w: W[k][c] fp32 (3 mats) -> Wt[col][k] bf16, col in [0,384).
// Also zeroes P[N] and desc[128].
// ---------------------------------------------------------------------------
__global__ __launch_bounds__(256) void prep_w(
    const float* __restrict__ Wq, const float* __restrict__ Wk,
    const float* __restrict__ Wv, ushort_t* __restrict__ Wt,
    int* __restrict__ P, unsigned long long* __restrict__ desc, int N)
{
    __shared__ float ld[32][33];
    int mat  = blockIdx.x >> 4;
    int tile = blockIdx.x & 15;
    int k0 = (tile >> 2) * 32, c0 = (tile & 3) * 32;
    const float* W = (mat == 0) ? Wq : (mat == 1) ? Wk : Wv;
    int t = threadIdx.x;
    {
        int k = t >> 3, c4 = (t & 7) * 4;
        float4 f = *(const float4*)&W[(size_t)(k0 + k) * 128 + c0 + c4];
        ld[k][c4 + 0] = f.x; ld[k][c4 + 1] = f.y;
        ld[k][c4 + 2] = f.z; ld[k][c4 + 3] = f.w;
    }
    __syncthreads();
    {
        int c = t >> 3, kg = (t & 7) * 4;
        union { ushort_t h[4]; uint2 u; } o;
        o.h[0] = f2bf(ld[kg + 0][c]); o.h[1] = f2bf(ld[kg + 1][c]);
        o.h[2] = f2bf(ld[kg + 2][c]); o.h[3] = f2bf(ld[kg + 3][c]);
        *(uint2*)&Wt[((size_t)(mat * 128 + c0 + c)) * 128 + k0 + kg] = o.u;
    }
    int t0 = blockIdx.x * 256 + threadIdx.x;
    for (int i = t0; i < N; i += 48 * 256) P[i] = 0;
    if (t0 < 128) desc[t0] = 0ULL;
}

// ---------------------------------------------------------------------------
// gemm_histo (persistent): 512 blocks x 384 thr (2 blocks/CU, 3 waves/SIMD).
// Prologue: every block issues its share of degree-histogram atomics (~4 per
// thread, fire-and-forget -> drain overlaps the GEMM).
// Then each wave loads its 16 B-fragments from Wt ONCE (64 VGPRs) and the
// block grid-strides over 64-row tiles: stage A in LDS (k-packed, 65-pad),
// 64 MFMAs/wave, epilogue LDS-transpose in 4 quarters -> coalesced dwordx4
// stores to qkv[N][384] bf16.
// ---------------------------------------------------------------------------
__global__ __launch_bounds__(384, 3) void gemm_histo(
    const float* __restrict__ x, const ushort_t* __restrict__ Wt,
    const float* __restrict__ bq, const float* __restrict__ bk,
    const float* __restrict__ bv,
    const int* __restrict__ ei, int* __restrict__ P,
    ushort_t* __restrict__ qkv,
    int N, int E, int ntiles)
{
    // ---- histogram prologue ----
    {
        int gtid   = (int)blockIdx.x * 384 + threadIdx.x;
        int stride = (int)gridDim.x * 384;
        for (int e = gtid; e < E; e += stride)
            atomicAdd(&P[ei[E + e]], 1);
    }

    __shared__ ushort_t sh[8320];     // 16640 B

    const int tid  = threadIdx.x;
    const int w    = tid >> 6;        // wave 0..5
    const int quad = (tid >> 4) & 3;
    const int l15  = tid & 15;
    const int colg = w << 6;          // col base 0..320

    // ---- load B fragments once: 16 x bf16x8 = 64 VGPRs ----
    bf16x8 bfr[4][4];
#pragma unroll
    for (int kt = 0; kt < 4; kt++)
#pragma unroll
        for (int cs = 0; cs < 4; cs++) {
            int col = colg + cs * 16 + l15;
            bfr[kt][cs] = *(const bf16x8*)&Wt[(size_t)col * 128 + kt * 32 + quad * 8];
        }

    const int mat = w >> 1;           // 0=Q,1=K,2=V
    const float* Bp = (mat == 0) ? bq : (mat == 1) ? bk : bv;
    float bias[4];
#pragma unroll
    for (int cs = 0; cs < 4; cs++)
        bias[cs] = Bp[((w & 1) << 6) + cs * 16 + l15];

    // ---- persistent loop over row tiles ----
    for (int tile = blockIdx.x; tile < ntiles; tile += gridDim.x) {
        const int row0 = tile * 64;
        __syncthreads();   // protect sh from previous iteration's readers

        // stage A: 64 rows x 128 k, bf16, k-packed [kc(16)][row(65 pad)][8]
        for (int ch = tid; ch < 1024; ch += 384) {
            int row = ch >> 4;
            int kc  = ch & 15;
            int grow = row0 + row; if (grow > N - 1) grow = N - 1;
            const float* xp = x + (size_t)grow * IN_DIM + kc * 8;
            float4 f0 = *(const float4*)xp;
            float4 f1 = *(const float4*)(xp + 4);
            union { ushort_t h[8]; uint4 u; } tt;
            tt.h[0] = f2bf(f0.x); tt.h[1] = f2bf(f0.y);
            tt.h[2] = f2bf(f0.z); tt.h[3] = f2bf(f0.w);
            tt.h[4] = f2bf(f1.x); tt.h[5] = f2bf(f1.y);
            tt.h[6] = f2bf(f1.z); tt.h[7] = f2bf(f1.w);
            *(uint4*)&sh[(kc * 65 + row) * 8] = tt.u;
        }
        __syncthreads();

        f32x4 acc[4][4];
#pragma unroll
        for (int r = 0; r < 4; r++)
#pragma unroll
            for (int cs = 0; cs < 4; cs++) acc[r][cs] = (f32x4){0.f, 0.f, 0.f, 0.f};

#pragma unroll
        for (int kt = 0; kt < 4; kt++) {
            int kc = kt * 4 + quad;
            bf16x8 af[4];
#pragma unroll
            for (int r = 0; r < 4; r++)
                af[r] = *(const bf16x8*)&sh[(kc * 65 + r * 16 + l15) * 8];
#pragma unroll
            for (int r = 0; r < 4; r++)
#pragma unroll
                for (int cs = 0; cs < 4; cs++)
                    acc[r][cs] = __builtin_amdgcn_mfma_f32_16x16x32_bf16(
                        af[r], bfr[kt][cs], acc[r][cs], 0, 0, 0);
        }

        // epilogue: bias + cvt, LDS transpose in 4 quarters of 16 rows
#define EPS 392
#pragma unroll
        for (int qq = 0; qq < 4; qq++) {
            __syncthreads();
            int lrow = quad << 2;
#pragma unroll
            for (int cs = 0; cs < 4; cs++) {
                int col = (w << 6) + cs * 16 + l15;
#pragma unroll
                for (int reg = 0; reg < 4; reg++)
                    sh[(lrow + reg) * EPS + col] = f2bf(acc[qq][cs][reg] + bias[cs]);
            }
            __syncthreads();
#pragma unroll
            for (int i = 0; i < 2; i++) {
                int c = tid + i * 384;
                int row = c / 48;
                int col = (c % 48) * 8;
                int grow = row0 + qq * 16 + row;
                if (grow < N) {
                    uint4 val = *(const uint4*)&sh[row * EPS + col];
                    *(uint4*)&qkv[(size_t)grow * QKVD + col] = val;
                }
            }
        }
#undef EPS
    }
}

// ---------------------------------------------------------------------------
// Single-pass exclusive scan over P[N] (decoupled lookback).
// ---------------------------------------------------------------------------
__global__ __launch_bounds__(1024) void scan_onepass(
    int* __restrict__ P, unsigned long long* __restrict__ desc, int N)
{
    __shared__ int sdata[1024];
    __shared__ int s_prefix;
    int b = blockIdx.x;
    int i = b * 1024 + threadIdx.x;
    int v = (i < N) ? P[i] : 0;
    sdata[threadIdx.x] = v;
    __syncthreads();
    for (int off = 1; off < 1024; off <<= 1) {
        int t = (threadIdx.x >= off) ? sdata[threadIdx.x - off] : 0;
        __syncthreads();
        sdata[threadIdx.x] += t;
        __syncthreads();
    }
    int incl  = sdata[threadIdx.x];
    int total = sdata[1023];

    if (threadIdx.x == 0) {
        unsigned long long st1 = ((unsigned long long)((b == 0) ? 2 : 1) << 32)
                                 | (uint_t)total;
        __hip_atomic_store(&desc[b], st1, __ATOMIC_RELEASE, __HIP_MEMORY_SCOPE_AGENT);
        int prefix = 0;
        if (b > 0) {
            int bb = b - 1;
            for (;;) {
                unsigned long long d = __hip_atomic_load(
                    &desc[bb], __ATOMIC_ACQUIRE, __HIP_MEMORY_SCOPE_AGENT);
                uint_t st = (uint_t)(d >> 32);
                if (st == 0) continue;
                prefix += (int)(uint_t)(d & 0xFFFFFFFFu);
                if (st == 2) break;
                bb--;
            }
            __hip_atomic_store(&desc[b],
                ((unsigned long long)2 << 32) | (uint_t)(prefix + total),
                __ATOMIC_RELEASE, __HIP_MEMORY_SCOPE_AGENT);
        }
        s_prefix = prefix;
    }
    __syncthreads();
    if (i < N) P[i] = s_prefix + incl - v;   // exclusive
}

__global__ __launch_bounds__(256) void scatter(
    const int* __restrict__ ei, int* __restrict__ P,
    int* __restrict__ sorted_src, int E)
{
    int e0 = (blockIdx.x * 256 + threadIdx.x) * 4;
    if (e0 + 4 <= E) {
        int4 s4 = *(const int4*)&ei[e0];
        int4 d4 = *(const int4*)&ei[E + e0];
        sorted_src[atomicAdd(&P[d4.x], 1)] = s4.x;
        sorted_src[atomicAdd(&P[d4.y], 1)] = s4.y;
        sorted_src[atomicAdd(&P[d4.z], 1)] = s4.z;
        sorted_src[atomicAdd(&P[d4.w], 1)] = s4.w;
    } else {
        for (int e = e0; e < E; e++) {
            int pos = atomicAdd(&P[ei[E + e]], 1);
            sorted_src[pos] = ei[e];
        }
    }
}

// ---------------------------------------------------------------------------
// Segmented attention reduce + fused normalize. 16 lanes per node
// (4 nodes/wave): lane g holds dims [8g, 8g+8); one shfl_xor(1) per head dot.
// ---------------------------------------------------------------------------
__global__ __launch_bounds__(256) void segment_attn(
    const ushort_t* __restrict__ qkv,
    const int* __restrict__ P, const int* __restrict__ sorted_src,
    float* __restrict__ out, int N)
{
    int n = (blockIdx.x * 256 + threadIdx.x) >> 4;
    int g = threadIdx.x & 15;
    if (n >= N) return;
    int start = (n == 0) ? 0 : P[n - 1];
    int end   = P[n];
    int deg   = end - start;

    const uint_t* qrow = (const uint_t*)(qkv + (size_t)n * QKVD);
    uint4 qu = *(const uint4*)(qrow + g * 4);
    float q0 = bf2f((ushort_t)(qu.x & 0xFFFF)), q1 = bf2f((ushort_t)(qu.x >> 16));
    float q2 = bf2f((ushort_t)(qu.y & 0xFFFF)), q3 = bf2f((ushort_t)(qu.y >> 16));
    float q4 = bf2f((ushort_t)(qu.z & 0xFFFF)), q5 = bf2f((ushort_t)(qu.z >> 16));
    float q6 = bf2f((ushort_t)(qu.w & 0xFFFF)), q7 = bf2f((ushort_t)(qu.w >> 16));

    float a0 = 0.f, a1 = 0.f, a2 = 0.f, a3 = 0.f;
    float a4 = 0.f, a5 = 0.f, a6 = 0.f, a7 = 0.f, z = 0.f;

    int myidx = (g < deg) ? sorted_src[start + g] : 0;
    int wbase = (threadIdx.x & 63) & 48;

#define PROC(ku, vu)                                                       \
    {                                                                      \
        float p = bf2f((ushort_t)((ku).x & 0xFFFF)) * q0                   \
                + bf2f((ushort_t)((ku).x >> 16))    * q1                   \
                + bf2f((ushort_t)((ku).y & 0xFFFF)) * q2                   \
                + bf2f((ushort_t)((ku).y >> 16))    * q3                   \
                + bf2f((ushort_t)((ku).z & 0xFFFF)) * q4                   \
                + bf2f((ushort_t)((ku).z >> 16))    * q5                   \
                + bf2f((ushort_t)((ku).w & 0xFFFF)) * q6                   \
                + bf2f((ushort_t)((ku).w >> 16))    * q7;                  \
        p += __shfl_xor(p, 1);                                             \
        p = fminf(fmaxf(p * 0.25f, -5.f), 5.f);                            \
        float s = __expf(p);                                               \
        a0 += bf2f((ushort_t)((vu).x & 0xFFFF)) * s;                       \
        a1 += bf2f((ushort_t)((vu).x >> 16))    * s;                       \
        a2 += bf2f((ushort_t)((vu).y & 0xFFFF)) * s;                       \
        a3 += bf2f((ushort_t)((vu).y >> 16))    * s;                       \
        a4 += bf2f((ushort_t)((vu).z & 0xFFFF)) * s;                       \
        a5 += bf2f((ushort_t)((vu).z >> 16))    * s;                       \
        a6 += bf2f((ushort_t)((vu).w & 0xFFFF)) * s;                       \
        a7 += bf2f((ushort_t)((vu).w >> 16))    * s;                       \
        z += s;                                                            \
    }

    int cnt = (deg < 16) ? deg : 16;
    int t = 0;
    for (; t + 2 <= cnt; t += 2) {
        int s0 = __shfl(myidx, wbase + t);
        int s1 = __shfl(myidx, wbase + t + 1);
        const uint_t* kv0 = (const uint_t*)(qkv + (size_t)s0 * QKVD + 128);
        const uint_t* kv1 = (const uint_t*)(qkv + (size_t)s1 * QKVD + 128);
        uint4 ku0 = *(const uint4*)(kv0 + g * 4);
        uint4 ku1 = *(const uint4*)(kv1 + g * 4);
        uint4 vu0 = *(const uint4*)(kv0 + 64 + g * 4);
        uint4 vu1 = *(const uint4*)(kv1 + 64 + g * 4);
        PROC(ku0, vu0); PROC(ku1, vu1);
    }
    if (t < cnt) {
        int s0 = __shfl(myidx, wbase + t);
        const uint_t* kv0 = (const uint_t*)(qkv + (size_t)s0 * QKVD + 128);
        uint4 ku0 = *(const uint4*)(kv0 + g * 4);
        uint4 vu0 = *(const uint4*)(kv0 + 64 + g * 4);
        PROC(ku0, vu0);
    }
    for (int j = start + 16; j < end; j++) {
        int s0 = sorted_src[j];
        const uint_t* kv0 = (const uint_t*)(qkv + (size_t)s0 * QKVD + 128);
        uint4 ku0 = *(const uint4*)(kv0 + g * 4);
        uint4 vu0 = *(const uint4*)(kv0 + 64 + g * 4);
        PROC(ku0, vu0);
    }
#undef PROC

    float inv = 1.f / (z + 1e-6f);
    float4 o0 = {a0 * inv, a1 * inv, a2 * inv, a3 * inv};
    float4 o1 = {a4 * inv, a5 * inv, a6 * inv, a7 * inv};
    float* ob = out + (size_t)n * OUTD + g * 8;
    *(float4*)ob = o0;
    *(float4*)(ob + 4) = o1;
}

extern "C" void kernel_launch(void* const* d_in, const int* in_sizes, int n_in,
                              void* d_out, int out_size, void* d_ws, size_t ws_size,
                              hipStream_t stream) {
    const float* x  = (const float*)d_in[0];
    const int*   ei = (const int*)d_in[1];
    const float* Wq = (const float*)d_in[4];
    const float* bq = (const float*)d_in[5];
    const float* Wk = (const float*)d_in[6];
    const float* bk = (const float*)d_in[7];
    const float* Wv = (const float*)d_in[8];
    const float* bv = (const float*)d_in[9];
    float* out = (float*)d_out;

    const int N = in_sizes[0] / IN_DIM;     // 100000
    const int E = in_sizes[1] / 2;          // 800000

    char* wsb = (char*)d_ws;
    ushort_t* qkv = (ushort_t*)wsb;                          // N*384 bf16
    ushort_t* Wt  = qkv + (size_t)N * QKVD;                  // 384*128 bf16
    int* P = (int*)(Wt + 384 * 128);                         // N ints
    unsigned long long* desc = (unsigned long long*)((char*)P + (size_t)N * 4);
    int* sorted = (int*)((char*)desc + 1024);                // E ints

    const int ntiles = (N + 63) / 64;       // 1563
    const int NB     = (N + 1023) / 1024;   // 98 scan blocks

    prep_w<<<48, 256, 0, stream>>>(Wq, Wk, Wv, Wt, P, desc, N);
    gemm_histo<<<512, 384, 0, stream>>>(
        x, Wt, bq, bk, bv, ei, P, qkv, N, E, ntiles);
    scan_onepass<<<NB, 1024, 0, stream>>>(P, desc, N);
    scatter<<<(E / 4 + 255) / 256, 256, 0, stream>>>(ei, P, sorted, E);
    segment_attn<<<((size_t)N * 16 + 255) / 256, 256, 0, stream>>>(
        qkv, P, sorted, out, N);
}